// Round 5
// 112.465 us; speedup vs baseline: 1.0090x; 1.0090x over previous
//
#include <hip/hip_runtime.h>
#include <hip/hip_bf16.h>

// MultiHeadAttention: B=2, S=2048, D=1024, H=16, key=head=64
// ROUND 5: bisection round. attn_fwd = exact round-0 verified structure
// (mfma(Q,K), P through LDS, Q staged via LDS) + ONLY the mask-fold bundle:
//   - transpose_v zeroes masked V rows (oa = sum p*m*V)
//   - la via bf16 mask-vector MFMA (replaces cndmask-mask + ones-MFMA)
// Isolates whether the mask-fold bundle (shared by all 4 failing rounds)
// is the defect, or whether it is clean (=> bug was in the in-reg-P path).

#define SEQ 2048
#define DIM 1024
#define NPROJ 1024

typedef __bf16 bf16x8 __attribute__((ext_vector_type(8)));
typedef float floatx4 __attribute__((ext_vector_type(4)));
typedef float floatx16 __attribute__((ext_vector_type(16)));

__device__ inline unsigned short f2bf_bits(float x) {
  __hip_bfloat16 h = __float2bfloat16(x);
  return __builtin_bit_cast(unsigned short, h);
}

__device__ __forceinline__ void gload_lds16(const void* g, void* l) {
  __builtin_amdgcn_global_load_lds((const __attribute__((address_space(1))) void*)g,
                                   (__attribute__((address_space(3))) void*)l, 16, 0, 0);
}

// ---------------------------------------------------------------------------
// Kernel 0: q,k,v fp32 -> bf16 (xb = 3 contiguous [4096x1024] bf16 planes)
// ---------------------------------------------------------------------------
__global__ __launch_bounds__(256) void cvt_x(
    const float* __restrict__ q, const float* __restrict__ k, const float* __restrict__ v,
    unsigned short* __restrict__ xb)
{
  const float* X = blockIdx.z == 0 ? q : (blockIdx.z == 1 ? k : v);
  unsigned short* O = xb + (size_t)blockIdx.z * 4096 * 1024;
  int i0 = blockIdx.x * 256 + threadIdx.x;
  #pragma unroll
  for (int it = 0; it < 4; ++it) {
    int i = i0 + it * 262144;           // 1M float4 groups total
    float4 f = *reinterpret_cast<const float4*>(&X[(size_t)i * 4]);
    ushort4 o;
    o.x = f2bf_bits(f.x); o.y = f2bf_bits(f.y);
    o.z = f2bf_bits(f.z); o.w = f2bf_bits(f.w);
    *reinterpret_cast<ushort4*>(&O[(size_t)i * 4]) = o;
  }
}

// ---------------------------------------------------------------------------
// Kernel 1: W [1024x1024] fp32 -> W^T bf16; Wq scaled by 0.125*log2e
// ---------------------------------------------------------------------------
__global__ __launch_bounds__(256) void transpose_w(
    const float* __restrict__ Wq, const float* __restrict__ Wk, const float* __restrict__ Wv,
    unsigned short* __restrict__ WqT, unsigned short* __restrict__ WkT, unsigned short* __restrict__ WvT)
{
  const float* W = blockIdx.z == 0 ? Wq : (blockIdx.z == 1 ? Wk : Wv);
  unsigned short* WT = blockIdx.z == 0 ? WqT : (blockIdx.z == 1 ? WkT : WvT);
  const float sc = (blockIdx.z == 0) ? 0.1803368801f : 1.0f;
  __shared__ float tile[64][65];
  const int k0 = blockIdx.x * 64;
  const int n0 = blockIdx.y * 64;
  const int t = threadIdx.x;
  #pragma unroll
  for (int it = 0; it < 4; ++it) {
    int idx = t + (it << 8);
    int r = idx >> 4, c4 = (idx & 15) << 2;
    float4 v = *reinterpret_cast<const float4*>(&W[(k0 + r) * DIM + n0 + c4]);
    tile[r][c4 + 0] = v.x; tile[r][c4 + 1] = v.y;
    tile[r][c4 + 2] = v.z; tile[r][c4 + 3] = v.w;
  }
  __syncthreads();
  #pragma unroll
  for (int it = 0; it < 4; ++it) {
    int idx = t + (it << 8);
    int r = idx >> 4, c4 = (idx & 15) << 2;
    ushort4 o;
    o.x = f2bf_bits(tile[c4 + 0][r] * sc);
    o.y = f2bf_bits(tile[c4 + 1][r] * sc);
    o.z = f2bf_bits(tile[c4 + 2][r] * sc);
    o.w = f2bf_bits(tile[c4 + 3][r] * sc);
    *reinterpret_cast<ushort4*>(&WT[(n0 + r) * DIM + k0 + c4]) = o;
  }
}

// ---------------------------------------------------------------------------
// Kernel 2: Y = bf16( X @ W ), X bf16 [4096x1024], B = W^T bf16.
// 128x128 tile, BK=32, double-buffered global_load_lds, 32 KB LDS.
// ---------------------------------------------------------------------------
__global__ __launch_bounds__(256, 4) void proj_gemm(
    const unsigned short* __restrict__ xb,
    const unsigned short* __restrict__ WqT, const unsigned short* __restrict__ WkT,
    const unsigned short* __restrict__ WvT,
    unsigned short* __restrict__ qw, unsigned short* __restrict__ kw, unsigned short* __restrict__ vw)
{
  const unsigned short* X = xb + (size_t)blockIdx.z * 4096 * 1024;
  const unsigned short* WT = blockIdx.z == 0 ? WqT : (blockIdx.z == 1 ? WkT : WvT);
  unsigned short* Y = blockIdx.z == 0 ? qw : (blockIdx.z == 1 ? kw : vw);

  __shared__ unsigned short Al[2][128 * 32];  // [m][k] bf16, 64B rows, swizzled chunks
  __shared__ unsigned short Bl[2][128 * 32];  // [n][k]

  const int m0 = blockIdx.x * 128, n0 = blockIdx.y * 128;
  const int t = threadIdx.x;
  const int lane = t & 63;
  const int wid = t >> 6;
  const int wm = (wid >> 1) << 6, wn = (wid & 1) << 6;
  const int qd = lane >> 4, ln = lane & 15;

  auto stage = [&](int ks, int bi) {
    const int kb = ks << 6;  // byte offset along k (32 bf16 = 64 B)
    #pragma unroll
    for (int i = 0; i < 2; ++i) {
      int p = t + (i << 8);
      int r = p >> 2, c = p & 3;
      int f = (r + (r >> 2)) & 3;
      gload_lds16((const char*)X + (size_t)(m0 + r) * 2048 + kb + ((c ^ f) << 4),
                  (char*)&Al[bi][0] + p * 16);
      gload_lds16((const char*)WT + (size_t)(n0 + r) * 2048 + kb + ((c ^ f) << 4),
                  (char*)&Bl[bi][0] + p * 16);
    }
  };

  floatx4 acc[4][4] = {};
  stage(0, 0);

  for (int ks = 0; ks < 32; ++ks) {
    __syncthreads();
    if (ks + 1 < 32) stage(ks + 1, (ks + 1) & 1);
    const int bi = ks & 1;
    bf16x8 af[4], bfr[4];
    #pragma unroll
    for (int mb = 0; mb < 4; ++mb) {
      int m = wm + mb * 16 + ln;
      int fm = (m + (m >> 2)) & 3;
      af[mb] = *reinterpret_cast<const bf16x8*>(&Al[bi][m * 32 + ((qd ^ fm) << 3)]);
    }
    #pragma unroll
    for (int nb = 0; nb < 4; ++nb) {
      int n = wn + nb * 16 + ln;
      int fn = (n + (n >> 2)) & 3;
      bfr[nb] = *reinterpret_cast<const bf16x8*>(&Bl[bi][n * 32 + ((qd ^ fn) << 3)]);
    }
    #pragma unroll
    for (int mb = 0; mb < 4; ++mb)
      #pragma unroll
      for (int nb = 0; nb < 4; ++nb)
        acc[mb][nb] = __builtin_amdgcn_mfma_f32_16x16x32_bf16(af[mb], bfr[nb], acc[mb][nb], 0, 0, 0);
  }
  #pragma unroll
  for (int mb = 0; mb < 4; ++mb)
    #pragma unroll
    for (int nb = 0; nb < 4; ++nb)
      #pragma unroll
      for (int i = 0; i < 4; ++i) {
        int m = m0 + wm + mb * 16 + qd * 4 + i;
        int n = n0 + wn + nb * 16 + ln;
        Y[(size_t)m * NPROJ + n] = f2bf_bits(acc[mb][nb][i]);
      }
}

// ---------------------------------------------------------------------------
// Kernel 3: vw [B*S][H*64] -> vt [B][H][64(d)][S], LDS-tiled 64x64.
// Masked key rows are zeroed (folds the attention mask into V for the PV
// matmul). Also emits mb[b][s] = bf16(mask) for the rowsum MFMA operand.
// ---------------------------------------------------------------------------
__global__ __launch_bounds__(256) void transpose_v(
    const unsigned short* __restrict__ vw, const int* __restrict__ vmask,
    unsigned short* __restrict__ vt, unsigned short* __restrict__ mb)
{
  if (blockIdx.y == 0 && blockIdx.x < 16) {
    int i = blockIdx.x * 256 + threadIdx.x;
    mb[i] = vmask[i] ? 0x3F80 : 0;   // bf16 1.0 or 0.0
  }
  __shared__ unsigned short tile[64 * 64];  // chunk-rotated
  const int t = threadIdx.x;
  const int s0 = blockIdx.x * 64;
  const int bh = blockIdx.y;
  const int b = bh >> 4, h = bh & 15;
  #pragma unroll
  for (int it = 0; it < 2; ++it) {
    int p = t + (it << 8);
    int s = p >> 3, c = p & 7;
    int cp = (c + (s >> 3) + (s & 7)) & 7;
    int4 d = *reinterpret_cast<const int4*>(&vw[(size_t)(b * SEQ + s0 + s) * NPROJ + h * 64 + c * 8]);
    if (vmask[b * SEQ + s0 + s] == 0) { d.x = 0; d.y = 0; d.z = 0; d.w = 0; }
    *reinterpret_cast<int4*>(&tile[s * 64 + cp * 8]) = d;
  }
  __syncthreads();
  #pragma unroll
  for (int it = 0; it < 2; ++it) {
    int d = (t >> 3) + (it << 5), sc = t & 7;
    struct { alignas(16) unsigned short u[8]; } o;
    #pragma unroll
    for (int j = 0; j < 8; ++j) {
      int s = sc * 8 + j;
      int cp = ((d >> 3) + (s >> 3) + (s & 7)) & 7;
      o.u[j] = tile[s * 64 + cp * 8 + (d & 7)];
    }
    *reinterpret_cast<int4*>(&vt[(size_t)(bh * 64 + d) * SEQ + s0 + sc * 8]) =
        *reinterpret_cast<const int4*>(o.u);
  }
}

// ---------------------------------------------------------------------------
// Kernel 4: flash attention — round-0 verified structure.
// grid (bh=32, q-tiles=16), 256 thr. MFMA 32x32x16, K-tile 64, exp2 max-free
// softmax, P through LDS (stride 72). ONLY change vs round 0: mask folded
// into zeroed V (oa) + bf16 mask-vector MFMA (la) instead of per-key cndmask
// + ones-MFMA. LDS: P 18432 | Kl 16384 | Vl 16384 | Ml 256 = 51456 B.
// ---------------------------------------------------------------------------
__global__ __launch_bounds__(256, 3) void attn_fwd(
    const unsigned short* __restrict__ qw, const unsigned short* __restrict__ kw,
    const unsigned short* __restrict__ vt, const unsigned short* __restrict__ mb,
    float* __restrict__ out)
{
  extern __shared__ char smem[];
  unsigned short* P  = (unsigned short*)smem;                 // 128*72 ushort = 18432 B
  unsigned short* Kl = (unsigned short*)(smem + 18432);       // 2 * 64*64 = 16384 B
  unsigned short* Vl = (unsigned short*)(smem + 34816);       // 16384 B
  unsigned short* Ml = (unsigned short*)(smem + 51200);       // 2 * 64 bf16 = 256 B

  const int t = threadIdx.x, lane = t & 63, wid = t >> 6;
  const int l5 = lane & 31, hi = lane >> 5;
  const int bh = blockIdx.x;
  const int q0 = blockIdx.y * 128;
  const int b = bh >> 4, h = bh & 15;
  const int base = b * SEQ;
  const int wq = wid * 32;

  auto stage = [&](int kt, int bi) {
    const int k0 = kt << 6;
    #pragma unroll
    for (int i = 0; i < 2; ++i) {
      int rb = wid * 16 + i * 8;
      int r = rb + (lane >> 3);
      int sw = ((lane & 7) ^ (r & 7)) << 4;
      gload_lds16((const char*)kw + ((size_t)((base + k0 + r) * NPROJ + h * 64) << 1) + sw,
                  (char*)&Kl[bi * 4096] + rb * 128);
      gload_lds16((const char*)vt + ((size_t)((bh * 64 + r) * SEQ + k0) << 1) + sw,
                  (char*)&Vl[bi * 4096] + rb * 128);
    }
    if (wid == 3 && lane < 8)
      gload_lds16((const char*)mb + ((size_t)(base + k0 + lane * 8) << 1), (char*)&Ml[bi * 64]);
  };

  // stage Q (128 x 64 bf16) into P area
  #pragma unroll
  for (int i = 0; i < 4; ++i) {
    int idx = t + (i << 8);
    int r = idx >> 3, c8 = (idx & 7) << 3;
    *reinterpret_cast<int4*>(&P[r * 72 + c8]) =
        *reinterpret_cast<const int4*>(&qw[(size_t)((base + q0 + r) * NPROJ + h * 64 + c8)]);
  }
  __syncthreads();
  bf16x8 qf[4];
  #pragma unroll
  for (int kk = 0; kk < 4; ++kk)
    qf[kk] = *reinterpret_cast<const bf16x8*>(&P[(wq + l5) * 72 + kk * 16 + hi * 8]);

  floatx16 oa0 = {}, oa1 = {}, la = {};
  stage(0, 0);

  #pragma unroll 2
  for (int kt = 0; kt < SEQ / 64; ++kt) {
    __syncthreads();
    if (kt + 1 < SEQ / 64) stage(kt + 1, (kt + 1) & 1);
    const int bi = kt & 1;

    floatx16 s0 = {}, s1 = {};
    #pragma unroll
    for (int kk = 0; kk < 4; ++kk) {
      int ph = ((kk * 2 + hi) ^ (l5 & 7)) << 3;
      bf16x8 b0 = *reinterpret_cast<const bf16x8*>(&Kl[bi * 4096 + l5 * 64 + ph]);
      bf16x8 b1 = *reinterpret_cast<const bf16x8*>(&Kl[bi * 4096 + (32 + l5) * 64 + ph]);
      s0 = __builtin_amdgcn_mfma_f32_32x32x16_bf16(qf[kk], b0, s0, 0, 0, 0);
      s1 = __builtin_amdgcn_mfma_f32_32x32x16_bf16(qf[kk], b1, s1, 0, 0, 0);
    }

    // unmasked exp2 P (mask handled via zeroed V for oa, mask-vector for la)
    #pragma unroll
    for (int r = 0; r < 16; ++r) {
      float p0 = __builtin_amdgcn_exp2f(s0[r]);
      float p1 = __builtin_amdgcn_exp2f(s1[r]);
      int row = wq + (r & 3) + ((r >> 2) << 3) + (hi << 2);
      P[row * 72 + l5] = f2bf_bits(p0);
      P[row * 72 + 32 + l5] = f2bf_bits(p1);
    }

    #pragma unroll
    for (int kk = 0; kk < 4; ++kk) {
      bf16x8 ap = *reinterpret_cast<const bf16x8*>(&P[(wq + l5) * 72 + kk * 16 + hi * 8]);
      int ph = ((kk * 2 + hi) ^ (l5 & 7)) << 3;
      bf16x8 v0 = *reinterpret_cast<const bf16x8*>(&Vl[bi * 4096 + l5 * 64 + ph]);
      bf16x8 v1 = *reinterpret_cast<const bf16x8*>(&Vl[bi * 4096 + (32 + l5) * 64 + ph]);
      bf16x8 mf = *reinterpret_cast<const bf16x8*>(&Ml[bi * 64 + kk * 16 + hi * 8]);
      oa0 = __builtin_amdgcn_mfma_f32_32x32x16_bf16(ap, v0, oa0, 0, 0, 0);
      oa1 = __builtin_amdgcn_mfma_f32_32x32x16_bf16(ap, v1, oa1, 0, 0, 0);
      la  = __builtin_amdgcn_mfma_f32_32x32x16_bf16(ap, mf, la, 0, 0, 0);
    }
  }

  #pragma unroll
  for (int r = 0; r < 16; ++r) {
    int row = wq + (r & 3) + ((r >> 2) << 3) + (hi << 2);
    float inv = 1.0f / la[r];
    size_t o = (size_t)(base + q0 + row) * NPROJ + h * 64;
    out[o + l5] = oa0[r] * inv;
    out[o + 32 + l5] = oa1[r] * inv;
  }
}

// ---------------------------------------------------------------------------
extern "C" void kernel_launch(void* const* d_in, const int* in_sizes, int n_in,
                              void* d_out, int out_size, void* d_ws, size_t ws_size,
                              hipStream_t stream) {
  const float* q  = (const float*)d_in[0];
  const float* k  = (const float*)d_in[1];
  const float* v  = (const float*)d_in[2];
  const int* vm   = (const int*)d_in[3];
  const float* Wq = (const float*)d_in[4];
  const float* Wk = (const float*)d_in[5];
  const float* Wv = (const float*)d_in[6];
  float* out = (float*)d_out;

  unsigned short* ws = (unsigned short*)d_ws;
  unsigned short* WqT = ws + ((size_t)0 << 20);   // 2 MB each
  unsigned short* WkT = ws + ((size_t)1 << 20);
  unsigned short* WvT = ws + ((size_t)2 << 20);
  unsigned short* qw  = ws + ((size_t)3 << 20);   // 8 MB each
  unsigned short* kw  = ws + ((size_t)7 << 20);
  unsigned short* vw  = ws + ((size_t)11 << 20);
  unsigned short* xb  = ws + ((size_t)15 << 20);  // 24 MB (3 bf16 planes)
  unsigned short* vt  = ws + ((size_t)15 << 20);  // aliases xb (xb dead before transpose_v)
  unsigned short* mbv = WqT;                      // aliases WqT (dead after proj_gemm)

  cvt_x<<<dim3(1024, 1, 3), 256, 0, stream>>>(q, k, v, xb);
  transpose_w<<<dim3(16, 16, 3), 256, 0, stream>>>(Wq, Wk, Wv, WqT, WkT, WvT);
  proj_gemm<<<dim3(32, 8, 3), 256, 0, stream>>>(xb, WqT, WkT, WvT, qw, kw, vw);
  transpose_v<<<dim3(32, 32), 256, 0, stream>>>(vw, vm, vt, mbv);
  attn_fwd<<<dim3(32, 16), 256, 51456, stream>>>(qw, kw, vt, mbv, out);
}

// Round 6
// 101.403 us; speedup vs baseline: 1.1191x; 1.1091x over previous
//
#include <hip/hip_runtime.h>
#include <hip/hip_bf16.h>

// MultiHeadAttention: B=2, S=2048, D=1024, H=16, key=head=64
// cvt_x (q,k,v fp32->bf16) ; transpose_w (W->W^T bf16, Wq pre-scaled 0.125*log2e)
// proj_gemm (bf16 A via global_load_lds, BK=32 dbuf)
// transpose_v (vw -> vt[b][h][d][s], mask-zeroed rows, + bf16 mask vector mb)  [verified R5]
// attn_fwd: swapped QK^T (A=K,B=Q) with sigma-permuted K staging -> lane-local
// P keys 16kk+8hi+{0..7}; pack via scalar __float2bfloat16 (NO cvt_pk asm —
// R1-R4 failures isolate to that instruction's unpinned pack/round behavior).

#define SEQ 2048
#define DIM 1024
#define NPROJ 1024

typedef __bf16 bf16x8 __attribute__((ext_vector_type(8)));
typedef float floatx4 __attribute__((ext_vector_type(4)));
typedef float floatx16 __attribute__((ext_vector_type(16)));

__device__ inline unsigned short f2bf_bits(float x) {
  __hip_bfloat16 h = __float2bfloat16(x);
  return __builtin_bit_cast(unsigned short, h);
}

__device__ __forceinline__ void gload_lds16(const void* g, void* l) {
  __builtin_amdgcn_global_load_lds((const __attribute__((address_space(1))) void*)g,
                                   (__attribute__((address_space(3))) void*)l, 16, 0, 0);
}

// ---------------------------------------------------------------------------
// Kernel 0: q,k,v fp32 -> bf16 (xb = 3 contiguous [4096x1024] bf16 planes)
// ---------------------------------------------------------------------------
__global__ __launch_bounds__(256) void cvt_x(
    const float* __restrict__ q, const float* __restrict__ k, const float* __restrict__ v,
    unsigned short* __restrict__ xb)
{
  const float* X = blockIdx.z == 0 ? q : (blockIdx.z == 1 ? k : v);
  unsigned short* O = xb + (size_t)blockIdx.z * 4096 * 1024;
  int i0 = blockIdx.x * 256 + threadIdx.x;
  #pragma unroll
  for (int it = 0; it < 4; ++it) {
    int i = i0 + it * 262144;           // 1M float4 groups total
    float4 f = *reinterpret_cast<const float4*>(&X[(size_t)i * 4]);
    ushort4 o;
    o.x = f2bf_bits(f.x); o.y = f2bf_bits(f.y);
    o.z = f2bf_bits(f.z); o.w = f2bf_bits(f.w);
    *reinterpret_cast<ushort4*>(&O[(size_t)i * 4]) = o;
  }
}

// ---------------------------------------------------------------------------
// Kernel 1: W [1024x1024] fp32 -> W^T bf16; Wq scaled by 0.125*log2e
// ---------------------------------------------------------------------------
__global__ __launch_bounds__(256) void transpose_w(
    const float* __restrict__ Wq, const float* __restrict__ Wk, const float* __restrict__ Wv,
    unsigned short* __restrict__ WqT, unsigned short* __restrict__ WkT, unsigned short* __restrict__ WvT)
{
  const float* W = blockIdx.z == 0 ? Wq : (blockIdx.z == 1 ? Wk : Wv);
  unsigned short* WT = blockIdx.z == 0 ? WqT : (blockIdx.z == 1 ? WkT : WvT);
  const float sc = (blockIdx.z == 0) ? 0.1803368801f : 1.0f;
  __shared__ float tile[64][65];
  const int k0 = blockIdx.x * 64;
  const int n0 = blockIdx.y * 64;
  const int t = threadIdx.x;
  #pragma unroll
  for (int it = 0; it < 4; ++it) {
    int idx = t + (it << 8);
    int r = idx >> 4, c4 = (idx & 15) << 2;
    float4 v = *reinterpret_cast<const float4*>(&W[(k0 + r) * DIM + n0 + c4]);
    tile[r][c4 + 0] = v.x; tile[r][c4 + 1] = v.y;
    tile[r][c4 + 2] = v.z; tile[r][c4 + 3] = v.w;
  }
  __syncthreads();
  #pragma unroll
  for (int it = 0; it < 4; ++it) {
    int idx = t + (it << 8);
    int r = idx >> 4, c4 = (idx & 15) << 2;
    ushort4 o;
    o.x = f2bf_bits(tile[c4 + 0][r] * sc);
    o.y = f2bf_bits(tile[c4 + 1][r] * sc);
    o.z = f2bf_bits(tile[c4 + 2][r] * sc);
    o.w = f2bf_bits(tile[c4 + 3][r] * sc);
    *reinterpret_cast<ushort4*>(&WT[(n0 + r) * DIM + k0 + c4]) = o;
  }
}

// ---------------------------------------------------------------------------
// Kernel 2: Y = bf16( X @ W ), X bf16 [4096x1024], B = W^T bf16.
// 128x128 tile, BK=32, double-buffered global_load_lds, 32 KB LDS.
// ---------------------------------------------------------------------------
__global__ __launch_bounds__(256, 4) void proj_gemm(
    const unsigned short* __restrict__ xb,
    const unsigned short* __restrict__ WqT, const unsigned short* __restrict__ WkT,
    const unsigned short* __restrict__ WvT,
    unsigned short* __restrict__ qw, unsigned short* __restrict__ kw, unsigned short* __restrict__ vw)
{
  const unsigned short* X = xb + (size_t)blockIdx.z * 4096 * 1024;
  const unsigned short* WT = blockIdx.z == 0 ? WqT : (blockIdx.z == 1 ? WkT : WvT);
  unsigned short* Y = blockIdx.z == 0 ? qw : (blockIdx.z == 1 ? kw : vw);

  __shared__ unsigned short Al[2][128 * 32];  // [m][k] bf16, 64B rows, swizzled chunks
  __shared__ unsigned short Bl[2][128 * 32];  // [n][k]

  const int m0 = blockIdx.x * 128, n0 = blockIdx.y * 128;
  const int t = threadIdx.x;
  const int lane = t & 63;
  const int wid = t >> 6;
  const int wm = (wid >> 1) << 6, wn = (wid & 1) << 6;
  const int qd = lane >> 4, ln = lane & 15;

  auto stage = [&](int ks, int bi) {
    const int kb = ks << 6;  // byte offset along k (32 bf16 = 64 B)
    #pragma unroll
    for (int i = 0; i < 2; ++i) {
      int p = t + (i << 8);
      int r = p >> 2, c = p & 3;
      int f = (r + (r >> 2)) & 3;
      gload_lds16((const char*)X + (size_t)(m0 + r) * 2048 + kb + ((c ^ f) << 4),
                  (char*)&Al[bi][0] + p * 16);
      gload_lds16((const char*)WT + (size_t)(n0 + r) * 2048 + kb + ((c ^ f) << 4),
                  (char*)&Bl[bi][0] + p * 16);
    }
  };

  floatx4 acc[4][4] = {};
  stage(0, 0);

  for (int ks = 0; ks < 32; ++ks) {
    __syncthreads();
    if (ks + 1 < 32) stage(ks + 1, (ks + 1) & 1);
    const int bi = ks & 1;
    bf16x8 af[4], bfr[4];
    #pragma unroll
    for (int mb = 0; mb < 4; ++mb) {
      int m = wm + mb * 16 + ln;
      int fm = (m + (m >> 2)) & 3;
      af[mb] = *reinterpret_cast<const bf16x8*>(&Al[bi][m * 32 + ((qd ^ fm) << 3)]);
    }
    #pragma unroll
    for (int nb = 0; nb < 4; ++nb) {
      int n = wn + nb * 16 + ln;
      int fn = (n + (n >> 2)) & 3;
      bfr[nb] = *reinterpret_cast<const bf16x8*>(&Bl[bi][n * 32 + ((qd ^ fn) << 3)]);
    }
    #pragma unroll
    for (int mb = 0; mb < 4; ++mb)
      #pragma unroll
      for (int nb = 0; nb < 4; ++nb)
        acc[mb][nb] = __builtin_amdgcn_mfma_f32_16x16x32_bf16(af[mb], bfr[nb], acc[mb][nb], 0, 0, 0);
  }
  #pragma unroll
  for (int mb = 0; mb < 4; ++mb)
    #pragma unroll
    for (int nb = 0; nb < 4; ++nb)
      #pragma unroll
      for (int i = 0; i < 4; ++i) {
        int m = m0 + wm + mb * 16 + qd * 4 + i;
        int n = n0 + wn + nb * 16 + ln;
        Y[(size_t)m * NPROJ + n] = f2bf_bits(acc[mb][nb][i]);
      }
}

// ---------------------------------------------------------------------------
// Kernel 3: vw [B*S][H*64] -> vt [B][H][64(d)][S], LDS-tiled 64x64.
// Masked key rows are zeroed (folds the attention mask into V for the PV
// matmul). Also emits mb[b][s] = bf16(mask) for the rowsum MFMA operand.
// ---------------------------------------------------------------------------
__global__ __launch_bounds__(256) void transpose_v(
    const unsigned short* __restrict__ vw, const int* __restrict__ vmask,
    unsigned short* __restrict__ vt, unsigned short* __restrict__ mb)
{
  if (blockIdx.y == 0 && blockIdx.x < 16) {
    int i = blockIdx.x * 256 + threadIdx.x;
    mb[i] = vmask[i] ? 0x3F80 : 0;   // bf16 1.0 or 0.0
  }
  __shared__ unsigned short tile[64 * 64];  // chunk-rotated
  const int t = threadIdx.x;
  const int s0 = blockIdx.x * 64;
  const int bh = blockIdx.y;
  const int b = bh >> 4, h = bh & 15;
  #pragma unroll
  for (int it = 0; it < 2; ++it) {
    int p = t + (it << 8);
    int s = p >> 3, c = p & 7;
    int cp = (c + (s >> 3) + (s & 7)) & 7;
    int4 d = *reinterpret_cast<const int4*>(&vw[(size_t)(b * SEQ + s0 + s) * NPROJ + h * 64 + c * 8]);
    if (vmask[b * SEQ + s0 + s] == 0) { d.x = 0; d.y = 0; d.z = 0; d.w = 0; }
    *reinterpret_cast<int4*>(&tile[s * 64 + cp * 8]) = d;
  }
  __syncthreads();
  #pragma unroll
  for (int it = 0; it < 2; ++it) {
    int d = (t >> 3) + (it << 5), sc = t & 7;
    struct { alignas(16) unsigned short u[8]; } o;
    #pragma unroll
    for (int j = 0; j < 8; ++j) {
      int s = sc * 8 + j;
      int cp = ((d >> 3) + (s >> 3) + (s & 7)) & 7;
      o.u[j] = tile[s * 64 + cp * 8 + (d & 7)];
    }
    *reinterpret_cast<int4*>(&vt[(size_t)(bh * 64 + d) * SEQ + s0 + sc * 8]) =
        *reinterpret_cast<const int4*>(o.u);
  }
}

// ---------------------------------------------------------------------------
// Kernel 4: flash attention. grid (bh=32, q-tiles=16), 256 thr.
// Swapped QK^T: s = mfma(K, Q) -> each lane holds a full P-row for its
// q = lane&31. K rows staged PERMUTED: LDS row r holds K[sigma(r)],
// sigma = swap(bit2,bit3). Then s0/s1 reg r on lane (l5,hi) = score for
// key 16*(r>>3) + 8*hi + (r&7) (+32 for s1) -> pe[8kk+j] = key 16kk+8hi+j,
// pa is pure in-lane sequential packing via scalar RNE converts.
// Mask: V rows pre-zeroed (oa); rowsum uses staged bf16 mask vector (la).
// Dynamic LDS 33,024 B.
// ---------------------------------------------------------------------------
__global__ __launch_bounds__(256, 2) void attn_fwd(
    const unsigned short* __restrict__ qw, const unsigned short* __restrict__ kw,
    const unsigned short* __restrict__ vt, const unsigned short* __restrict__ mb,
    float* __restrict__ out)
{
  extern __shared__ char smem[];
  unsigned short* Kl = (unsigned short*)smem;             // 2 * 64*64 bf16 = 16384 B
  unsigned short* Vl = (unsigned short*)(smem + 16384);   // 16384 B
  unsigned short* Ml = (unsigned short*)(smem + 32768);   // 2 * 64 bf16 = 256 B

  const int t = threadIdx.x, lane = t & 63, wid = t >> 6;
  const int l5 = lane & 31, hi = lane >> 5;
  const int bh = blockIdx.x;
  const int q0 = blockIdx.y * 128;
  const int b = bh >> 4, h = bh & 15;
  const int base = b * SEQ;
  const int wq = wid * 32;

  auto stage = [&](int kt, int bi) {
    const int k0 = kt << 6;
    #pragma unroll
    for (int i = 0; i < 2; ++i) {
      int rb = wid * 16 + i * 8;
      int r = rb + (lane >> 3);
      // sigma(r): swap bit2<->bit3 — K row sigma(r) lands in LDS row r, so
      // QK^T D-row crow corresponds to actual key sigma(crow), giving each
      // lane keys 16kk+8hi+{0..7} (PV A-fragment native order).
      int rsrc = (r & ~12) | ((r & 4) << 1) | ((r & 8) >> 1);
      int sw = ((lane & 7) ^ (r & 7)) << 4;
      gload_lds16((const char*)kw + ((size_t)((base + k0 + rsrc) * NPROJ + h * 64) << 1) + sw,
                  (char*)&Kl[bi * 4096] + rb * 128);
      gload_lds16((const char*)vt + ((size_t)((bh * 64 + r) * SEQ + k0) << 1) + sw,
                  (char*)&Vl[bi * 4096] + rb * 128);
    }
    if (wid == 3 && lane < 8)
      gload_lds16((const char*)mb + ((size_t)(base + k0 + lane * 8) << 1), (char*)&Ml[bi * 64]);
  };

  // Q fragment straight from global: row = q, 8 contiguous bf16 per lane.
  bf16x8 qf[4];
  {
    const unsigned short* qptr =
        qw + (size_t)(base + q0 + wq + l5) * NPROJ + h * 64 + hi * 8;
    #pragma unroll
    for (int kk = 0; kk < 4; ++kk)
      qf[kk] = *reinterpret_cast<const bf16x8*>(qptr + kk * 16);
  }

  floatx16 oa0 = {}, oa1 = {}, la = {};
  stage(0, 0);

  #pragma unroll 2
  for (int kt = 0; kt < SEQ / 64; ++kt) {
    __syncthreads();
    if (kt + 1 < SEQ / 64) stage(kt + 1, (kt + 1) & 1);
    const int bi = kt & 1;

    // QK^T swapped: A = permuted K rows, B = Q cols (q = lane&31).
    floatx16 s0 = {}, s1 = {};
    #pragma unroll
    for (int kk = 0; kk < 4; ++kk) {
      int ph = ((kk * 2 + hi) ^ (l5 & 7)) << 3;
      bf16x8 k0f = *reinterpret_cast<const bf16x8*>(&Kl[bi * 4096 + l5 * 64 + ph]);
      bf16x8 k1f = *reinterpret_cast<const bf16x8*>(&Kl[bi * 4096 + (32 + l5) * 64 + ph]);
      s0 = __builtin_amdgcn_mfma_f32_32x32x16_bf16(k0f, qf[kk], s0, 0, 0, 0);
      s1 = __builtin_amdgcn_mfma_f32_32x32x16_bf16(k1f, qf[kk], s1, 0, 0, 0);
    }

    // exp2 in-register. With sigma: s0[r] = key 16*(r>>3)+8hi+(r&7); s1 +32.
    // So pe[i] = P[key = 16*(i>>3) + 8hi + (i&7)] with pe[16..31] = keys+32,
    // i.e. pa[kk] element j = pe[8*kk + j]. Scalar RNE converts (no cvt_pk).
    float pe[32];
    #pragma unroll
    for (int r = 0; r < 16; ++r) {
      pe[r]      = __builtin_amdgcn_exp2f(s0[r]);
      pe[16 + r] = __builtin_amdgcn_exp2f(s1[r]);
    }

    #pragma unroll
    for (int kk = 0; kk < 4; ++kk) {
      struct alignas(16) { unsigned short u[8]; } pk;
      #pragma unroll
      for (int j = 0; j < 8; ++j) pk.u[j] = f2bf_bits(pe[8 * kk + j]);
      bf16x8 pa = __builtin_bit_cast(bf16x8, pk);
      int ph = ((kk * 2 + hi) ^ (l5 & 7)) << 3;
      bf16x8 v0 = *reinterpret_cast<const bf16x8*>(&Vl[bi * 4096 + l5 * 64 + ph]);
      bf16x8 v1 = *reinterpret_cast<const bf16x8*>(&Vl[bi * 4096 + (32 + l5) * 64 + ph]);
      bf16x8 mf = *reinterpret_cast<const bf16x8*>(&Ml[bi * 64 + kk * 16 + hi * 8]);
      oa0 = __builtin_amdgcn_mfma_f32_32x32x16_bf16(pa, v0, oa0, 0, 0, 0);
      oa1 = __builtin_amdgcn_mfma_f32_32x32x16_bf16(pa, v1, oa1, 0, 0, 0);
      la  = __builtin_amdgcn_mfma_f32_32x32x16_bf16(pa, mf, la, 0, 0, 0);
    }
  }

  #pragma unroll
  for (int r = 0; r < 16; ++r) {
    int row = wq + (r & 3) + ((r >> 2) << 3) + (hi << 2);
    float inv = 1.0f / la[r];
    size_t o = (size_t)(base + q0 + row) * NPROJ + h * 64;
    out[o + l5] = oa0[r] * inv;
    out[o + 32 + l5] = oa1[r] * inv;
  }
}

// ---------------------------------------------------------------------------
extern "C" void kernel_launch(void* const* d_in, const int* in_sizes, int n_in,
                              void* d_out, int out_size, void* d_ws, size_t ws_size,
                              hipStream_t stream) {
  const float* q  = (const float*)d_in[0];
  const float* k  = (const float*)d_in[1];
  const float* v  = (const float*)d_in[2];
  const int* vm   = (const int*)d_in[3];
  const float* Wq = (const float*)d_in[4];
  const float* Wk = (const float*)d_in[5];
  const float* Wv = (const float*)d_in[6];
  float* out = (float*)d_out;

  unsigned short* ws = (unsigned short*)d_ws;
  unsigned short* WqT = ws + ((size_t)0 << 20);   // 2 MB each
  unsigned short* WkT = ws + ((size_t)1 << 20);
  unsigned short* WvT = ws + ((size_t)2 << 20);
  unsigned short* qw  = ws + ((size_t)3 << 20);   // 8 MB each
  unsigned short* kw  = ws + ((size_t)7 << 20);
  unsigned short* vw  = ws + ((size_t)11 << 20);
  unsigned short* xb  = ws + ((size_t)15 << 20);  // 24 MB (3 bf16 planes)
  unsigned short* vt  = ws + ((size_t)15 << 20);  // aliases xb (xb dead before transpose_v)
  unsigned short* mbv = WqT;                      // aliases WqT (dead after proj_gemm)

  cvt_x<<<dim3(1024, 1, 3), 256, 0, stream>>>(q, k, v, xb);
  transpose_w<<<dim3(16, 16, 3), 256, 0, stream>>>(Wq, Wk, Wv, WqT, WkT, WvT);
  proj_gemm<<<dim3(32, 8, 3), 256, 0, stream>>>(xb, WqT, WkT, WvT, qw, kw, vw);
  transpose_v<<<dim3(32, 32), 256, 0, stream>>>(vw, vm, vt, mbv);
  attn_fwd<<<dim3(32, 16), 256, 33024, stream>>>(qw, kw, vt, mbv, out);
}